// Round 1
// baseline (1392.010 us; speedup 1.0000x reference)
//
#include <hip/hip_runtime.h>
#include <stdint.h>

// ---------------- problem constants ----------------
#define G_   128
#define DC   128
#define DM   64
#define DP   64
#define DFF  512
#define TT   64      // tokens per block tile
#define LDA  136     // bf16 LDS row stride (128 + 8 pad -> 2-way bank alias only)

typedef __attribute__((ext_vector_type(8))) __bf16 bf16x8;
typedef __attribute__((ext_vector_type(4))) float  f32x4;

union F8 { uint4 u; bf16x8 b; };

__device__ __forceinline__ ushort f2b(float f) {
  union { float f; uint32_t u; } x; x.f = f;
  uint32_t u = x.u;
  return (ushort)((u + 0x7FFFu + ((u >> 16) & 1u)) >> 16);   // RNE
}
__device__ __forceinline__ float b2f(ushort h) {
  union { uint32_t u; float f; } x; x.u = ((uint32_t)h) << 16;
  return x.f;
}
__device__ __forceinline__ f32x4 zero4() { f32x4 z = {0.f, 0.f, 0.f, 0.f}; return z; }

// ---------------- weight transpose+bf16 pre-pass ----------------
// src: (G, K, N) f32 row-major  ->  dst: (G, Npad, K) bf16, rows >= N zero-filled
__global__ __launch_bounds__(256) void transpose_w(const float* __restrict__ src,
                                                   ushort* __restrict__ dst,
                                                   int K, int N, int Npad) {
  __shared__ float tile[32][33];
  const int g = blockIdx.y;
  const int ntiles = Npad >> 5;
  const int kt = blockIdx.x / ntiles, nt = blockIdx.x % ntiles;
  const int tx = threadIdx.x, ty = threadIdx.y;
#pragma unroll
  for (int j = 0; j < 4; ++j) {
    int k = kt * 32 + ty + j * 8;
    int n = nt * 32 + tx;
    float v = (n < N) ? src[((size_t)g * K + k) * N + n] : 0.f;
    tile[ty + j * 8][tx] = v;
  }
  __syncthreads();
#pragma unroll
  for (int j = 0; j < 4; ++j) {
    int n = nt * 32 + ty + j * 8;
    int k = kt * 32 + tx;
    dst[((size_t)g * Npad + n) * K + k] = f2b(tile[tx][ty + j * 8]);
  }
}

// ---------------- n-split MFMA GEMM helper ----------------
// A: LDS bf16, 64 x K, stride LDA. Bt: (N x K) bf16 row-major (global or LDS).
// Wave w computes n-tiles n == w (mod 4), all 4 m-tiles. A-frags cached in regs.
// D layout: row = m*16 + (lane>>4)*4 + r, col = n*16 + (lane&15).
template <int KT, int NT, typename EPI>
__device__ __forceinline__ void gemm_ns(const ushort* A, const ushort* Bt, int ldb,
                                        int wave, int lane, EPI epi) {
  const int cold = lane & 15;
  const int kl = (lane >> 4) << 3;
  F8 af[4][KT];
#pragma unroll
  for (int m = 0; m < 4; ++m)
#pragma unroll
    for (int kk = 0; kk < KT; ++kk)
      af[m][kk].u = *(const uint4*)(A + (m * 16 + cold) * LDA + kk * 32 + kl);
  for (int n = wave; n < NT; n += 4) {
    f32x4 acc[4] = {zero4(), zero4(), zero4(), zero4()};
#pragma unroll
    for (int kk = 0; kk < KT; ++kk) {
      F8 bf;
      bf.u = *(const uint4*)(Bt + (size_t)(n * 16 + cold) * ldb + kk * 32 + kl);
#pragma unroll
      for (int m = 0; m < 4; ++m)
        acc[m] = __builtin_amdgcn_mfma_f32_16x16x32_bf16(af[m][kk].b, bf.b, acc[m], 0, 0, 0);
    }
#pragma unroll
    for (int m = 0; m < 4; ++m) epi(n, m, acc[m]);
  }
}

// ---------------- fused main kernel ----------------
__global__ __launch_bounds__(256, 2) void cc_main(
    const float* __restrict__ x_col, const float* __restrict__ pm_state,
    const float* __restrict__ em_state, const float* __restrict__ z_hat_prev,
    const float* __restrict__ ffn_norm_w, const float* __restrict__ ffn_norm_b,
    const float* __restrict__ ffn_up_b, const float* __restrict__ ffn_down_b,
    const float* __restrict__ pm_up_b, const float* __restrict__ pm_down_b,
    const float* __restrict__ em_up_b, const float* __restrict__ em_down_b,
    const float* __restrict__ post_b, const float* __restrict__ enc_b,
    const float* __restrict__ pred_b, const float* __restrict__ gain_b,
    const ushort* __restrict__ Wpmu, const ushort* __restrict__ Wpmd,
    const ushort* __restrict__ Wemu, const ushort* __restrict__ Wemd,
    const ushort* __restrict__ Wenc, const ushort* __restrict__ Wgain,
    const ushort* __restrict__ Wpred, const ushort* __restrict__ Wup,
    const ushort* __restrict__ Wdn, const ushort* __restrict__ Wpost,
    float* __restrict__ out) {
  __shared__ __align__(16) ushort XB[TT * LDA];   // current x (bf16)
  __shared__ __align__(16) ushort A0[TT * LDA];   // scratch A
  __shared__ __align__(16) ushort A1[TT * LDA];   // scratch A
  __shared__ __align__(16) ushort PS[16 * 72];    // pm_state (16 x 64)
  __shared__ __align__(16) ushort PSTT[64 * 40];  // pm_state^T (64 x 32, k 16..31 = 0)
  __shared__ __align__(16) ushort ES[64 * 72];    // em_state (64 x 64)
  __shared__ __align__(16) ushort EST[64 * 72];   // em_state^T (64 x 64)

  const int tid = threadIdx.x;
  const int lane = tid & 63, wave = tid >> 6;
  // XCD-aware swizzle: keep all 32 tiles of one g on one XCD (perf heuristic only)
  const int phys = blockIdx.x;
  const int g = (phys & 7) + ((phys >> 8) << 3);
  const int tile = (phys >> 3) & 31;
  const int t0 = tile * TT;
  const int b = t0 >> 9;      // 512 tokens per batch
  const int xg = g >> 4;      // B-index (G = 8*16)
  const int cold = lane & 15;
  const int rr = (lane >> 4) << 2;
  const int kl = (lane >> 4) << 3;

  float* const o_xout = out;
  float* const o_z    = out + 33554432;
  float* const o_zhat = out + 50331648;
  float* const o_sur  = out + 67108864;
  float* const o_kc   = out + 67371008;
  float* const o_vp   = out + 84148224;
  float* const o_gate = out + 100925440;
  float* const o_qn   = out + 101187584;
  float* const o_vc   = out + 117964800;
  float* const o_wn   = out + 134742016;
  float* const o_s4   = out + 135004160;

  // ---- load x tile + states ----
  for (int i = tid; i < TT * 32; i += 256) {   // 64 rows x 32 float4
    int row = i >> 5, c4 = (i & 31) << 2;
    const float4 v = *(const float4*)(x_col + ((size_t)(t0 + row) * G_ + g) * DC + c4);
    ushort4 h; h.x = f2b(v.x); h.y = f2b(v.y); h.z = f2b(v.z); h.w = f2b(v.w);
    *(ushort4*)(XB + row * LDA + c4) = h;
  }
  for (int i = tid; i < 16 * 64; i += 256) {
    int s = i >> 6, d = i & 63;
    ushort h = f2b(pm_state[(((size_t)b * 8 + xg) * 16 + s) * 64 + d]);
    PS[s * 72 + d] = h;
    PSTT[d * 40 + s] = h;
  }
  for (int i = tid; i < 64 * 16; i += 256) {   // zero K-pad of PSTT
    int d = i >> 4, s = 16 + (i & 15);
    PSTT[d * 40 + s] = 0;
  }
  for (int i = tid; i < 64 * 64; i += 256) {
    int s = i >> 6, d = i & 63;
    ushort h = f2b(em_state[(((size_t)b * 8 + xg) * 64 + s) * 64 + d]);
    ES[s * 72 + d] = h;
    EST[d * 72 + s] = h;
  }
  __syncthreads();

  // ---- S1: q_pm = x @ pm_up + b -> A0 (cols 0..63) ----
  gemm_ns<4, 4>(XB, Wpmu + (size_t)g * 8192, 128, wave, lane, [&](int n, int m, f32x4 a) {
    const int col = n * 16 + cold;
    const float bias = pm_up_b[g * 64 + col];
#pragma unroll
    for (int r = 0; r < 4; ++r) A0[(m * 16 + rr + r) * LDA + col] = f2b(a[r] + bias);
  });
  __syncthreads();

  // ---- S2: pm scores = q @ state^T * 0.125 -> A1 (cols 0..15); wave w = m-tile w ----
  {
    f32x4 acc = zero4();
#pragma unroll
    for (int kk = 0; kk < 2; ++kk) {
      F8 bf; bf.u = *(const uint4*)(PS + cold * 72 + kk * 32 + kl);
      F8 af; af.u = *(const uint4*)(A0 + (wave * 16 + cold) * LDA + kk * 32 + kl);
      acc = __builtin_amdgcn_mfma_f32_16x16x32_bf16(af.b, bf.b, acc, 0, 0, 0);
    }
#pragma unroll
    for (int r = 0; r < 4; ++r) A1[(wave * 16 + rr + r) * LDA + cold] = f2b(acc[r] * 0.125f);
  }
  __syncthreads();

  // ---- S2b: softmax over 16 slots (4 lanes/token), zero pad cols 16..31 ----
  {
    const int tk = tid >> 2, sub = tid & 3;
    float v[4]; float mx = -1e30f;
#pragma unroll
    for (int i = 0; i < 4; ++i) { v[i] = b2f(A1[tk * LDA + sub * 4 + i]); mx = fmaxf(mx, v[i]); }
    mx = fmaxf(mx, __shfl_xor(mx, 1, 4)); mx = fmaxf(mx, __shfl_xor(mx, 2, 4));
    float s = 0.f;
#pragma unroll
    for (int i = 0; i < 4; ++i) { v[i] = __expf(v[i] - mx); s += v[i]; }
    s += __shfl_xor(s, 1, 4); s += __shfl_xor(s, 2, 4);
    const float inv = 1.f / s;
#pragma unroll
    for (int i = 0; i < 4; ++i) A1[tk * LDA + sub * 4 + i] = f2b(v[i] * inv);
#pragma unroll
    for (int i = 0; i < 4; ++i) A1[tk * LDA + 16 + sub * 4 + i] = 0;
  }
  __syncthreads();

  // ---- S3: r_pm = att @ state -> A0 (cols 0..63) ----
  gemm_ns<1, 4>(A1, PSTT, 40, wave, lane, [&](int n, int m, f32x4 a) {
    const int col = n * 16 + cold;
#pragma unroll
    for (int r = 0; r < 4; ++r) A0[(m * 16 + rr + r) * LDA + col] = f2b(a[r]);
  });
  __syncthreads();

  // ---- S4: x += r_pm @ pm_down + b (update XB) ----
  gemm_ns<2, 8>(A0, Wpmd + (size_t)g * 8192, 64, wave, lane, [&](int n, int m, f32x4 a) {
    const int col = n * 16 + cold;
    const float bias = pm_down_b[g * 128 + col];
#pragma unroll
    for (int r = 0; r < 4; ++r) {
      const int row = m * 16 + rr + r;
      XB[row * LDA + col] = f2b(b2f(XB[row * LDA + col]) + a[r] + bias);
    }
  });
  __syncthreads();

  // ---- S5: q_em = x @ em_up + b -> A0 ----
  gemm_ns<4, 4>(XB, Wemu + (size_t)g * 8192, 128, wave, lane, [&](int n, int m, f32x4 a) {
    const int col = n * 16 + cold;
    const float bias = em_up_b[g * 64 + col];
#pragma unroll
    for (int r = 0; r < 4; ++r) A0[(m * 16 + rr + r) * LDA + col] = f2b(a[r] + bias);
  });
  __syncthreads();

  // ---- S6: em scores -> A1 (cols 0..63) ----
  gemm_ns<2, 4>(A0, ES, 72, wave, lane, [&](int n, int m, f32x4 a) {
    const int col = n * 16 + cold;
#pragma unroll
    for (int r = 0; r < 4; ++r) A1[(m * 16 + rr + r) * LDA + col] = f2b(a[r] * 0.125f);
  });
  __syncthreads();

  // ---- S6b: softmax over 64 slots ----
  {
    const int tk = tid >> 2, sub = tid & 3;
    float v[16]; float mx = -1e30f;
#pragma unroll
    for (int i = 0; i < 16; ++i) { v[i] = b2f(A1[tk * LDA + sub * 16 + i]); mx = fmaxf(mx, v[i]); }
    mx = fmaxf(mx, __shfl_xor(mx, 1, 4)); mx = fmaxf(mx, __shfl_xor(mx, 2, 4));
    float s = 0.f;
#pragma unroll
    for (int i = 0; i < 16; ++i) { v[i] = __expf(v[i] - mx); s += v[i]; }
    s += __shfl_xor(s, 1, 4); s += __shfl_xor(s, 2, 4);
    const float inv = 1.f / s;
#pragma unroll
    for (int i = 0; i < 16; ++i) A1[tk * LDA + sub * 16 + i] = f2b(v[i] * inv);
  }
  __syncthreads();

  // ---- S7: r_em = att @ state -> A0 ----
  gemm_ns<2, 4>(A1, EST, 72, wave, lane, [&](int n, int m, f32x4 a) {
    const int col = n * 16 + cold;
#pragma unroll
    for (int r = 0; r < 4; ++r) A0[(m * 16 + rr + r) * LDA + col] = f2b(a[r]);
  });
  __syncthreads();

  // ---- S8: x += r_em @ em_down + b ----
  gemm_ns<2, 8>(A0, Wemd + (size_t)g * 8192, 64, wave, lane, [&](int n, int m, f32x4 a) {
    const int col = n * 16 + cold;
    const float bias = em_down_b[g * 128 + col];
#pragma unroll
    for (int r = 0; r < 4; ++r) {
      const int row = m * 16 + rr + r;
      XB[row * LDA + col] = f2b(b2f(XB[row * LDA + col]) + a[r] + bias);
    }
  });
  __syncthreads();

  // ---- S9: z = x @ enc + b; write z; delta -> A0; z(bf16) -> A1 ----
  gemm_ns<4, 4>(XB, Wenc + (size_t)g * 8192, 128, wave, lane, [&](int n, int m, f32x4 a) {
    const int col = n * 16 + cold;
    const float bias = enc_b[g * 64 + col];
#pragma unroll
    for (int r = 0; r < 4; ++r) {
      const int row = m * 16 + rr + r;
      const size_t zi = ((size_t)(t0 + row) * G_ + g) * DP + col;
      const float zv = a[r] + bias;
      o_z[zi] = zv;
      const float dv = zv - z_hat_prev[zi];
      A0[row * LDA + col] = f2b(dv);
      A1[row * LDA + col] = f2b(zv);
    }
  });
  __syncthreads();

  // ---- S9b: surprise/gate/s4 from delta ----
  {
    const int tk = tid >> 2, sub = tid & 3;
    float s = 0.f;
#pragma unroll
    for (int i = 0; i < 16; ++i) { float d = b2f(A0[tk * LDA + sub * 16 + i]); s += d * d; }
    s += __shfl_xor(s, 1, 4); s += __shfl_xor(s, 2, 4);
    if (sub == 0) {
      const float sur = sqrtf(s);
      const size_t si = (size_t)(t0 + tk) * G_ + g;
      o_sur[si] = sur; o_s4[si] = sur;
      o_gate[si] = fminf(fmaxf(sur, 0.f), 1.f);
    }
  }
  // ---- S10: z_hat = z @ pred + b (reads A1, global write only) ----
  gemm_ns<2, 4>(A1, Wpred + (size_t)g * 4096, 64, wave, lane, [&](int n, int m, f32x4 a) {
    const int col = n * 16 + cold;
    const float bias = pred_b[g * 64 + col];
#pragma unroll
    for (int r = 0; r < 4; ++r) {
      const int row = m * 16 + rr + r;
      o_zhat[((size_t)(t0 + row) * G_ + g) * DP + col] = a[r] + bias;
    }
  });
  __syncthreads();

  // ---- S11: gain = 1 + 0.1*tanh(delta @ gain_w + b) -> A1 ----
  gemm_ns<2, 8>(A0, Wgain + (size_t)g * 8192, 64, wave, lane, [&](int n, int m, f32x4 a) {
    const int col = n * 16 + cold;
    const float bias = gain_b[g * 128 + col];
#pragma unroll
    for (int r = 0; r < 4; ++r)
      A1[(m * 16 + rr + r) * LDA + col] = f2b(1.f + 0.1f * tanhf(a[r] + bias));
  });
  __syncthreads();

  // ---- S12: h = LN(x)*w+b times gain -> A0 ----
  {
    const int tk = tid >> 2, sub = tid & 3;
    float xv[32]; float sm = 0.f, sq = 0.f;
#pragma unroll
    for (int i = 0; i < 32; ++i) {
      xv[i] = b2f(XB[tk * LDA + sub * 32 + i]);
      sm += xv[i]; sq += xv[i] * xv[i];
    }
    sm += __shfl_xor(sm, 1, 4); sm += __shfl_xor(sm, 2, 4);
    sq += __shfl_xor(sq, 1, 4); sq += __shfl_xor(sq, 2, 4);
    const float mu = sm * (1.f / 128.f);
    const float var = sq * (1.f / 128.f) - mu * mu;
    const float rstd = rsqrtf(var + 1e-5f);
#pragma unroll
    for (int i = 0; i < 32; ++i) {
      const int c = sub * 32 + i;
      float h = (xv[i] - mu) * rstd * ffn_norm_w[g * 128 + c] + ffn_norm_b[g * 128 + c];
      h *= b2f(A1[tk * LDA + c]);
      A0[tk * LDA + c] = f2b(h);
    }
  }
  __syncthreads();

  // ---- S13: FFN (chunked 4x128), x_out = x + down(gelu(up(h))) + b ----
  {
    f32x4 accD[4][2];
#pragma unroll
    for (int m = 0; m < 4; ++m)
#pragma unroll
      for (int nj = 0; nj < 2; ++nj) accD[m][nj] = zero4();
    for (int c = 0; c < 4; ++c) {
      gemm_ns<4, 8>(A0, Wup + (size_t)g * 65536 + (size_t)c * 16384, 128, wave, lane,
                    [&](int n, int m, f32x4 a) {
        const int col = n * 16 + cold;
        const float bias = ffn_up_b[g * 512 + c * 128 + col];
#pragma unroll
        for (int r = 0; r < 4; ++r) {
          float u = a[r] + bias;
          u = 0.5f * u * (1.f + erff(u * 0.70710678118654752f));   // exact gelu
          A1[(m * 16 + rr + r) * LDA + col] = f2b(u);
        }
      });
      __syncthreads();
      {
        F8 af[4][4];
#pragma unroll
        for (int m = 0; m < 4; ++m)
#pragma unroll
          for (int kk = 0; kk < 4; ++kk)
            af[m][kk].u = *(const uint4*)(A1 + (m * 16 + cold) * LDA + kk * 32 + kl);
#pragma unroll
        for (int nj = 0; nj < 2; ++nj) {
          const int n = wave + nj * 4;
#pragma unroll
          for (int kk = 0; kk < 4; ++kk) {
            F8 bf;
            bf.u = *(const uint4*)(Wdn + (size_t)g * 65536 + (size_t)(n * 16 + cold) * 512 +
                                   c * 128 + kk * 32 + kl);
#pragma unroll
            for (int m = 0; m < 4; ++m)
              accD[m][nj] = __builtin_amdgcn_mfma_f32_16x16x32_bf16(af[m][kk].b, bf.b, accD[m][nj], 0, 0, 0);
          }
        }
      }
      __syncthreads();
    }
    // epilogue: write x_out (global f32) and XB (bf16)
#pragma unroll
    for (int nj = 0; nj < 2; ++nj) {
      const int n = wave + nj * 4;
      const int col = n * 16 + cold;
      const float bias = ffn_down_b[g * 128 + col];
#pragma unroll
      for (int m = 0; m < 4; ++m) {
#pragma unroll
        for (int r = 0; r < 4; ++r) {
          const int row = m * 16 + rr + r;
          const float xo = b2f(XB[row * LDA + col]) + accD[m][nj][r] + bias;
          o_xout[((size_t)(t0 + row) * G_ + g) * DC + col] = xo;
          XB[row * LDA + col] = f2b(xo);
        }
      }
    }
  }
  __syncthreads();

  // ---- S14: proj = x_out @ post + b (N = 272 incl. zero pad) ----
  gemm_ns<4, 17>(XB, Wpost + (size_t)g * 36864, 128, wave, lane, [&](int n, int m, f32x4 a) {
#pragma unroll
    for (int r = 0; r < 4; ++r) {
      const int row = m * 16 + rr + r;
      const int t = t0 + row;
      if (n < 4) {                       // k_pre -> A0 cols 0..63
        const int col = n * 16 + cold;
        A0[row * LDA + col] = f2b(a[r] + post_b[g * 257 + col]);
      } else if (n < 8) {                // v_post direct
        const int col = n * 16 + cold;
        o_vp[((size_t)t * G_ + g) * DM + (col - 64)] = a[r] + post_b[g * 257 + col];
      } else if (n < 12) {               // k_cand_raw -> A0 cols 64..127
        const int col = n * 16 + cold;
        A0[row * LDA + (col - 64)] = f2b(a[r] + post_b[g * 257 + col]);
      } else if (n < 16) {               // v_cand direct
        const int col = n * 16 + cold;
        o_vc[((size_t)t * G_ + g) * DM + (col - 192)] = a[r] + post_b[g * 257 + col];
      } else if (cold == 0) {            // nov column (col 256)
        const float v = a[r] + post_b[g * 257 + 256];
        o_wn[(size_t)t * G_ + g] = 1.f / (1.f + __expf(-v));
      }
    }
  });
  __syncthreads();

  // ---- S15: k_cand = normalize(k_pre), q_nov = normalize(k_cand_raw) ----
  {
    const int tk = tid >> 2, sub = tid & 3;
    const size_t base = ((size_t)(t0 + tk) * G_ + g) * DM;
    float v[16]; float s = 0.f;
#pragma unroll
    for (int i = 0; i < 16; ++i) { v[i] = b2f(A0[tk * LDA + sub * 16 + i]); s += v[i] * v[i]; }
    s += __shfl_xor(s, 1, 4); s += __shfl_xor(s, 2, 4);
    float inv = 1.f / (sqrtf(s) + 1e-6f);
#pragma unroll
    for (int i = 0; i < 16; ++i) o_kc[base + sub * 16 + i] = v[i] * inv;
    s = 0.f;
#pragma unroll
    for (int i = 0; i < 16; ++i) { v[i] = b2f(A0[tk * LDA + 64 + sub * 16 + i]); s += v[i] * v[i]; }
    s += __shfl_xor(s, 1, 4); s += __shfl_xor(s, 2, 4);
    inv = 1.f / (sqrtf(s) + 1e-6f);
#pragma unroll
    for (int i = 0; i < 16; ++i) o_qn[base + sub * 16 + i] = v[i] * inv;
  }
}

// ---------------- launch ----------------
extern "C" void kernel_launch(void* const* d_in, const int* in_sizes, int n_in,
                              void* d_out, int out_size, void* d_ws, size_t ws_size,
                              hipStream_t stream) {
  (void)in_sizes; (void)n_in; (void)out_size; (void)ws_size;
  const float* x_col      = (const float*)d_in[0];
  const float* pm_state   = (const float*)d_in[1];
  const float* em_state   = (const float*)d_in[2];
  const float* z_hat_prev = (const float*)d_in[3];
  const float* ffn_norm_w = (const float*)d_in[4];
  const float* ffn_norm_b = (const float*)d_in[5];
  const float* ffn_up_w   = (const float*)d_in[6];
  const float* ffn_up_b   = (const float*)d_in[7];
  const float* ffn_down_w = (const float*)d_in[8];
  const float* ffn_down_b = (const float*)d_in[9];
  const float* pm_up_w    = (const float*)d_in[10];
  const float* pm_up_b    = (const float*)d_in[11];
  const float* pm_down_w  = (const float*)d_in[12];
  const float* pm_down_b  = (const float*)d_in[13];
  const float* em_up_w    = (const float*)d_in[14];
  const float* em_up_b    = (const float*)d_in[15];
  const float* em_down_w  = (const float*)d_in[16];
  const float* em_down_b  = (const float*)d_in[17];
  const float* post_w     = (const float*)d_in[18];
  const float* post_b     = (const float*)d_in[19];
  const float* enc_w      = (const float*)d_in[20];
  const float* enc_b      = (const float*)d_in[21];
  const float* pred_w     = (const float*)d_in[22];
  const float* pred_b     = (const float*)d_in[23];
  const float* gain_w     = (const float*)d_in[24];
  const float* gain_b     = (const float*)d_in[25];

  ushort* W = (ushort*)d_ws;   // bf16 transposed weights (element offsets)
  ushort* Wpmu  = W + 0;          // 128 * (64*128)
  ushort* Wpmd  = W + 1048576;    // 128 * (128*64)
  ushort* Wemu  = W + 2097152;
  ushort* Wemd  = W + 3145728;
  ushort* Wenc  = W + 4194304;
  ushort* Wgain = W + 5242880;
  ushort* Wpred = W + 6291456;    // 128 * (64*64)
  ushort* Wup   = W + 6815744;    // 128 * (512*128)
  ushort* Wdn   = W + 15204352;   // 128 * (128*512)
  ushort* Wpost = W + 23592960;   // 128 * (288*128)

  dim3 tb(32, 8);
  transpose_w<<<dim3(8, 128), tb, 0, stream>>>(pm_up_w,   Wpmu, 128, 64, 64);
  transpose_w<<<dim3(8, 128), tb, 0, stream>>>(pm_down_w, Wpmd, 64, 128, 128);
  transpose_w<<<dim3(8, 128), tb, 0, stream>>>(em_up_w,   Wemu, 128, 64, 64);
  transpose_w<<<dim3(8, 128), tb, 0, stream>>>(em_down_w, Wemd, 64, 128, 128);
  transpose_w<<<dim3(8, 128), tb, 0, stream>>>(enc_w,     Wenc, 128, 64, 64);
  transpose_w<<<dim3(8, 128), tb, 0, stream>>>(gain_w,    Wgain, 64, 128, 128);
  transpose_w<<<dim3(4, 128), tb, 0, stream>>>(pred_w,    Wpred, 64, 64, 64);
  transpose_w<<<dim3(64, 128), tb, 0, stream>>>(ffn_up_w,   Wup, 128, 512, 512);
  transpose_w<<<dim3(64, 128), tb, 0, stream>>>(ffn_down_w, Wdn, 512, 128, 128);
  transpose_w<<<dim3(36, 128), tb, 0, stream>>>(post_w,     Wpost, 128, 257, 288);

  cc_main<<<4096, 256, 0, stream>>>(
      x_col, pm_state, em_state, z_hat_prev, ffn_norm_w, ffn_norm_b,
      ffn_up_b, ffn_down_b, pm_up_b, pm_down_b, em_up_b, em_down_b,
      post_b, enc_b, pred_b, gain_b,
      Wpmu, Wpmd, Wemu, Wemd, Wenc, Wgain, Wpred, Wup, Wdn, Wpost,
      (float*)d_out);
}